// Round 1
// baseline (469.288 us; speedup 1.0000x reference)
//
#include <hip/hip_runtime.h>

#define B_ 16
#define N_ 1024
#define F_ 256
#define H_ 4
#define QDIM 128

__device__ __forceinline__ float leaky(float x) {
    return x >= 0.f ? x : 0.2f * x;
}

// robust fast tanh: 1 - 2/(e^{2x}+1); exp overflow/underflow saturate correctly
__device__ __forceinline__ float tanh_fast(float x) {
    float e2 = __expf(2.f * x);
    return 1.f - 2.f / (e2 + 1.f);
}

// ---------------------------------------------------------------------------
// K1: q[b,h,n], k[b,h,n] = a[h]·leaky(x[b,n,:]·W[h]) + b[h]
// grid = (512 row-tiles of 32, 2 {q,k}), block = 256
// Each thread owns 2 of the 512 (h,qdim) columns; rows staged in LDS.
// ---------------------------------------------------------------------------
__global__ __launch_bounds__(256) void qk_kernel(
    const float* __restrict__ x,
    const float* __restrict__ Wq, const float* __restrict__ aq, const float* __restrict__ bq,
    const float* __restrict__ Wk, const float* __restrict__ ak, const float* __restrict__ bk,
    float* __restrict__ qbuf, float* __restrict__ kbuf)
{
    const int tid = threadIdx.x;
    const int rt  = blockIdx.x;          // 32-row tile
    const bool isQ = (blockIdx.y == 0);
    const float* W  = isQ ? Wq : Wk;
    const float* av = isQ ? aq : ak;
    const float* bv = isQ ? bq : bk;
    float* out = isQ ? qbuf : kbuf;

    __shared__ float xs[32 * 256];       // 32 KB row tile
    const float4* xg = reinterpret_cast<const float4*>(x) + (size_t)rt * 2048;
    float4* xs4 = reinterpret_cast<float4*>(xs);
    #pragma unroll
    for (int it = 0; it < 8; ++it) xs4[it * 256 + tid] = xg[it * 256 + tid];
    __syncthreads();

    const int h0 = tid >> 7, q0 = tid & 127;       // col c0 = tid       (heads 0/1)
    const int c1 = tid + 256;
    const int h1 = c1 >> 7, q1 = c1 & 127;         // col c1 = tid + 256 (heads 2/3)

    float acc0[32], acc1[32];
    #pragma unroll
    for (int r = 0; r < 32; ++r) { acc0[r] = 0.f; acc1[r] = 0.f; }

    const float* W0 = W + h0 * (F_ * QDIM) + q0;
    const float* W1 = W + h1 * (F_ * QDIM) + q1;

    for (int f4 = 0; f4 < F_; f4 += 4) {
        const float w0a = W0[(f4 + 0) * QDIM], w0b = W0[(f4 + 1) * QDIM];
        const float w0c = W0[(f4 + 2) * QDIM], w0d = W0[(f4 + 3) * QDIM];
        const float w1a = W1[(f4 + 0) * QDIM], w1b = W1[(f4 + 1) * QDIM];
        const float w1c = W1[(f4 + 2) * QDIM], w1d = W1[(f4 + 3) * QDIM];
        #pragma unroll
        for (int r = 0; r < 32; ++r) {
            const float4 xv = *reinterpret_cast<const float4*>(&xs[r * 256 + f4]);
            acc0[r] = fmaf(xv.x, w0a, acc0[r]);
            acc0[r] = fmaf(xv.y, w0b, acc0[r]);
            acc0[r] = fmaf(xv.z, w0c, acc0[r]);
            acc0[r] = fmaf(xv.w, w0d, acc0[r]);
            acc1[r] = fmaf(xv.x, w1a, acc1[r]);
            acc1[r] = fmaf(xv.y, w1b, acc1[r]);
            acc1[r] = fmaf(xv.z, w1c, acc1[r]);
            acc1[r] = fmaf(xv.w, w1d, acc1[r]);
        }
    }

    // v = a[c]*leaky(hidden); reduce the 128 qdim columns per head.
    // Wave w holds 64 consecutive qdim cols of one head per colset.
    const float a0 = av[h0 * QDIM + q0];
    const float a1 = av[h1 * QDIM + q1];
    __shared__ float part[4][2][32];     // [wave][colset][row]
    const int wav = tid >> 6;
    const int lane = tid & 63;
    #pragma unroll
    for (int r = 0; r < 32; ++r) {
        float v0 = a0 * leaky(acc0[r]);
        float v1 = a1 * leaky(acc1[r]);
        #pragma unroll
        for (int m = 1; m < 64; m <<= 1) {
            v0 += __shfl_xor(v0, m, 64);
            v1 += __shfl_xor(v1, m, 64);
        }
        if (lane == 0) { part[wav][0][r] = v0; part[wav][1][r] = v1; }
    }
    __syncthreads();

    if (tid < 128) {
        const int h = tid >> 5, r = tid & 31;
        const int cs = h >> 1;           // colset: heads 0/1 in cs0, 2/3 in cs1
        const int wb = (h & 1) * 2;      // waves 0,1 vs 2,3
        const float val = part[wb][cs][r] + part[wb + 1][cs][r] + bv[h];
        const int row = rt * 32 + r;
        const int b = row >> 10, n = row & 1023;
        out[(b * H_ + h) * N_ + n] = val;
    }
}

// ---------------------------------------------------------------------------
// K2: scores + row-norm + masked column-sum, fused. One pass over e.
// grid = (64 i-chunks of 16, B), block = 256. Wave = one head; lane owns 16 j.
// w[b,h,j] += mask_i * tanh((q_i+k_j)*e_mod[i,j]) / (||row_i||+1e-7)
// ---------------------------------------------------------------------------
__global__ __launch_bounds__(256) void attn_kernel(
    const float* __restrict__ e,
    const float* __restrict__ qbuf, const float* __restrict__ kbuf,
    const float* __restrict__ mask, const float* __restrict__ epsp,
    float* __restrict__ wbuf)
{
    const int tid  = threadIdx.x;
    const int wav  = tid >> 6;           // head
    const int lane = tid & 63;
    const int b    = blockIdx.y;
    const int i0   = blockIdx.x * 16;
    const int jbase = lane * 16;
    const float epsv = epsp[0];
    const bool dl = (lane == blockIdx.x);    // this lane's 16 j's contain the diagonal

    const float* krow = kbuf + (b * H_ + wav) * N_ + jbase;
    float kk[16];
    #pragma unroll
    for (int u = 0; u < 16; u += 4) {
        const float4 kv = *reinterpret_cast<const float4*>(krow + u);
        kk[u] = kv.x; kk[u + 1] = kv.y; kk[u + 2] = kv.z; kk[u + 3] = kv.w;
    }

    float wacc[16];
    #pragma unroll
    for (int u = 0; u < 16; ++u) wacc[u] = 0.f;

    const float* qrow  = qbuf + (b * H_ + wav) * N_;
    const float* mrow  = mask + b * N_;
    const float* ebase = e + ((size_t)b << 20);

    #pragma unroll
    for (int ii = 0; ii < 16; ++ii) {
        const int i = i0 + ii;
        const float qi = qrow[i];
        const float mi = mrow[i];
        const float* erow = ebase + ((size_t)i << 10) + jbase;
        float p[16];
        #pragma unroll
        for (int u4 = 0; u4 < 4; ++u4) {
            float4 evv = *reinterpret_cast<const float4*>(erow + u4 * 4);
            if (dl && (ii >> 2) == u4) {     // compile-time after unroll
                const int c = ii & 3;
                if      (c == 0) evv.x += epsv;
                else if (c == 1) evv.y += epsv;
                else if (c == 2) evv.z += epsv;
                else             evv.w += epsv;
            }
            p[u4 * 4 + 0] = tanh_fast((qi + kk[u4 * 4 + 0]) * evv.x);
            p[u4 * 4 + 1] = tanh_fast((qi + kk[u4 * 4 + 1]) * evv.y);
            p[u4 * 4 + 2] = tanh_fast((qi + kk[u4 * 4 + 2]) * evv.z);
            p[u4 * 4 + 3] = tanh_fast((qi + kk[u4 * 4 + 3]) * evv.w);
        }
        float ssl = 0.f;
        #pragma unroll
        for (int u = 0; u < 16; ++u) ssl = fmaf(p[u], p[u], ssl);
        #pragma unroll
        for (int m = 1; m < 64; m <<= 1) ssl += __shfl_xor(ssl, m, 64);
        const float scale = mi / (sqrtf(ssl) + 1e-7f);
        #pragma unroll
        for (int u = 0; u < 16; ++u) wacc[u] = fmaf(scale, p[u], wacc[u]);
    }

    float* wrow = wbuf + (b * H_ + wav) * N_ + jbase;
    #pragma unroll
    for (int u = 0; u < 16; ++u) atomicAdd(&wrow[u], wacc[u]);
}

// ---------------------------------------------------------------------------
// K3a: ypart[(b,h,jc), f] = sum_{j in chunk} w[b,h,j] * x[b,j,f]
// grid = 256 (= B*H*4 j-chunks), block = 256 (f)
// ---------------------------------------------------------------------------
__global__ __launch_bounds__(256) void ypart_kernel(
    const float* __restrict__ x, const float* __restrict__ wbuf,
    float* __restrict__ ypart)
{
    const int tid = threadIdx.x;         // f
    const int bx  = blockIdx.x;          // ((b*4+h)*4+jc)
    const int jc  = bx & 3;
    const int bh  = bx >> 2;
    const int b   = bh >> 2;
    const int j0  = jc * 256;
    const float* wrow = wbuf + bh * N_ + j0;
    const float* xcol = x + ((size_t)(b * N_ + j0)) * F_ + tid;
    float acc = 0.f;
    #pragma unroll 4
    for (int j = 0; j < 256; ++j) {
        acc = fmaf(wrow[j], xcol[(size_t)j * F_], acc);
    }
    ypart[bx * F_ + tid] = acc;
}

// ---------------------------------------------------------------------------
// K3b: out[b, h*128+v] = sum_f (sum_jc ypart) * Wv[h,f,v]
// grid = 64 (b*4+h), block = 256
// ---------------------------------------------------------------------------
__global__ __launch_bounds__(256) void pool_kernel(
    const float* __restrict__ ypart, const float* __restrict__ Wv,
    float* __restrict__ out)
{
    const int tid = threadIdx.x;
    const int bh  = blockIdx.x;
    const int h   = bh & 3;
    __shared__ float ys[256];
    ys[tid] = ypart[(bh * 4 + 0) * F_ + tid] + ypart[(bh * 4 + 1) * F_ + tid]
            + ypart[(bh * 4 + 2) * F_ + tid] + ypart[(bh * 4 + 3) * F_ + tid];
    __syncthreads();
    if (tid < 128) {
        float acc = 0.f;
        const float* wv = Wv + h * (F_ * 128) + tid;
        #pragma unroll 4
        for (int f = 0; f < F_; ++f) acc = fmaf(ys[f], wv[f * 128], acc);
        out[bh * 128 + tid] = acc;
    }
}

extern "C" void kernel_launch(void* const* d_in, const int* in_sizes, int n_in,
                              void* d_out, int out_size, void* d_ws, size_t ws_size,
                              hipStream_t stream) {
    const float* e    = (const float*)d_in[0];
    const float* x    = (const float*)d_in[1];
    const float* mask = (const float*)d_in[2];
    const float* eps  = (const float*)d_in[3];
    const float* Wq   = (const float*)d_in[4];
    const float* Wk   = (const float*)d_in[5];
    const float* Wv   = (const float*)d_in[6];
    const float* aq   = (const float*)d_in[7];
    const float* bq   = (const float*)d_in[8];
    const float* ak   = (const float*)d_in[9];
    const float* bk   = (const float*)d_in[10];

    float* qbuf  = (float*)d_ws;            // [B,H,N]   65536 f32
    float* kbuf  = qbuf + 65536;            // [B,H,N]   65536 f32
    float* wbuf  = kbuf + 65536;            // [B,H,N]   65536 f32 (atomic accum)
    float* ypart = wbuf + 65536;            // [B,H,4,F] 65536 f32
    float* outf  = (float*)d_out;

    hipMemsetAsync(wbuf, 0, 65536 * sizeof(float), stream);

    qk_kernel<<<dim3(512, 2), 256, 0, stream>>>(x, Wq, aq, bq, Wk, ak, bk, qbuf, kbuf);
    attn_kernel<<<dim3(64, 16), 256, 0, stream>>>(e, qbuf, kbuf, mask, eps, wbuf);
    ypart_kernel<<<256, 256, 0, stream>>>(x, wbuf, ypart);
    pool_kernel<<<64, 256, 0, stream>>>(ypart, Wv, outf);
}

// Round 2
// 194.088 us; speedup vs baseline: 2.4179x; 2.4179x over previous
//
#include <hip/hip_runtime.h>

#define B_ 16
#define N_ 1024
#define F_ 256
#define H_ 4
#define QDIM 128

__device__ __forceinline__ float leaky(float x) {
    return x >= 0.f ? x : 0.2f * x;
}

// fast tanh: 1 - 2/(e^{2x}+1) with HW rcp; exp saturation gives exact +/-1 tails
__device__ __forceinline__ float tanh_fast(float x) {
    float e2 = __expf(2.f * x);
    return 1.f - 2.f * __builtin_amdgcn_rcpf(e2 + 1.f);
}

// ---------------------------------------------------------------------------
// K1: q[b,h,n], k[b,h,n] = a[h]·leaky(x[b,n,:]·W[h]) + b[h]
// grid = (512 row-tiles of 32, 2 {q,k}), block = 256
// ---------------------------------------------------------------------------
__global__ __launch_bounds__(256) void qk_kernel(
    const float* __restrict__ x,
    const float* __restrict__ Wq, const float* __restrict__ aq, const float* __restrict__ bq,
    const float* __restrict__ Wk, const float* __restrict__ ak, const float* __restrict__ bk,
    float* __restrict__ qbuf, float* __restrict__ kbuf)
{
    const int tid = threadIdx.x;
    const int rt  = blockIdx.x;          // 32-row tile
    const bool isQ = (blockIdx.y == 0);
    const float* W  = isQ ? Wq : Wk;
    const float* av = isQ ? aq : ak;
    const float* bv = isQ ? bq : bk;
    float* out = isQ ? qbuf : kbuf;

    __shared__ float xs[32 * 256];       // 32 KB row tile
    const float4* xg = reinterpret_cast<const float4*>(x) + (size_t)rt * 2048;
    float4* xs4 = reinterpret_cast<float4*>(xs);
    #pragma unroll
    for (int it = 0; it < 8; ++it) xs4[it * 256 + tid] = xg[it * 256 + tid];
    __syncthreads();

    const int h0 = tid >> 7, q0 = tid & 127;       // col c0 = tid       (heads 0/1)
    const int c1 = tid + 256;
    const int h1 = c1 >> 7, q1 = c1 & 127;         // col c1 = tid + 256 (heads 2/3)

    float acc0[32], acc1[32];
    #pragma unroll
    for (int r = 0; r < 32; ++r) { acc0[r] = 0.f; acc1[r] = 0.f; }

    const float* W0 = W + h0 * (F_ * QDIM) + q0;
    const float* W1 = W + h1 * (F_ * QDIM) + q1;

    for (int f4 = 0; f4 < F_; f4 += 4) {
        const float w0a = W0[(f4 + 0) * QDIM], w0b = W0[(f4 + 1) * QDIM];
        const float w0c = W0[(f4 + 2) * QDIM], w0d = W0[(f4 + 3) * QDIM];
        const float w1a = W1[(f4 + 0) * QDIM], w1b = W1[(f4 + 1) * QDIM];
        const float w1c = W1[(f4 + 2) * QDIM], w1d = W1[(f4 + 3) * QDIM];
        #pragma unroll
        for (int r = 0; r < 32; ++r) {
            const float4 xv = *reinterpret_cast<const float4*>(&xs[r * 256 + f4]);
            acc0[r] = fmaf(xv.x, w0a, acc0[r]);
            acc0[r] = fmaf(xv.y, w0b, acc0[r]);
            acc0[r] = fmaf(xv.z, w0c, acc0[r]);
            acc0[r] = fmaf(xv.w, w0d, acc0[r]);
            acc1[r] = fmaf(xv.x, w1a, acc1[r]);
            acc1[r] = fmaf(xv.y, w1b, acc1[r]);
            acc1[r] = fmaf(xv.z, w1c, acc1[r]);
            acc1[r] = fmaf(xv.w, w1d, acc1[r]);
        }
    }

    const float a0 = av[h0 * QDIM + q0];
    const float a1 = av[h1 * QDIM + q1];
    __shared__ float part[4][2][32];     // [wave][colset][row]
    const int wav = tid >> 6;
    const int lane = tid & 63;
    #pragma unroll
    for (int r = 0; r < 32; ++r) {
        float v0 = a0 * leaky(acc0[r]);
        float v1 = a1 * leaky(acc1[r]);
        #pragma unroll
        for (int m = 1; m < 64; m <<= 1) {
            v0 += __shfl_xor(v0, m, 64);
            v1 += __shfl_xor(v1, m, 64);
        }
        if (lane == 0) { part[wav][0][r] = v0; part[wav][1][r] = v1; }
    }
    __syncthreads();

    if (tid < 128) {
        const int h = tid >> 5, r = tid & 31;
        const int cs = h >> 1;           // colset: heads 0/1 in cs0, 2/3 in cs1
        const int wb = (h & 1) * 2;      // waves 0,1 vs 2,3
        const float val = part[wb][cs][r] + part[wb + 1][cs][r] + bv[h];
        const int row = rt * 32 + r;
        const int b = row >> 10, n = row & 1023;
        out[(b * H_ + h) * N_ + n] = val;
    }
}

// ---------------------------------------------------------------------------
// K2: scores + row-norm + masked column partial-sums. One pass over e.
// grid = (32 i-chunks of 32, B), block = 256. Wave = head.
// Lane owns j = {lane + 64u : u=0..15} (stride-64 interleave) so the
// diagonal's u-slot (= i>>6) is BLOCK-UNIFORM -> no runtime reg indexing.
// Partials go to pbuf[ic][b][h][j] -- no atomics, no cross-block contention.
// ---------------------------------------------------------------------------
__global__ __launch_bounds__(256) void attn_kernel(
    const float* __restrict__ e,
    const float* __restrict__ qbuf, const float* __restrict__ kbuf,
    const float* __restrict__ mask, const float* __restrict__ epsp,
    float* __restrict__ pbuf)
{
    const int tid  = threadIdx.x;
    const int h    = tid >> 6;
    const int lane = tid & 63;
    const int b    = blockIdx.y;
    const int ic   = blockIdx.x;         // 32-row chunk
    const int i0   = ic * 32;
    const float epsv = epsp[0];
    const int udiag = ic >> 1;           // (i>>6) is constant across the chunk

    const float* kr = kbuf + (b * H_ + h) * N_ + lane;
    float kk[16];
    #pragma unroll
    for (int u = 0; u < 16; ++u) kk[u] = kr[u * 64];

    float wacc[16];
    #pragma unroll
    for (int u = 0; u < 16; ++u) wacc[u] = 0.f;

    const float* qrow  = qbuf + (b * H_ + h) * N_;
    const float* mrow  = mask + b * N_;
    const float* ebase = e + ((size_t)b << 20) + lane;

    #pragma unroll 2
    for (int ii = 0; ii < 32; ++ii) {
        const int i = i0 + ii;
        const float qi = qrow[i];
        const float* er = ebase + ((size_t)i << 10);
        const bool isdl = (lane == (i & 63));
        float p[16];
        float ssl = 0.f;
        #pragma unroll
        for (int u = 0; u < 16; ++u) {
            float ev = er[u * 64];
            if (u == udiag) ev += isdl ? epsv : 0.f;   // uniform branch on u
            p[u] = tanh_fast((qi + kk[u]) * ev);
            ssl = fmaf(p[u], p[u], ssl);
        }
        #pragma unroll
        for (int m = 1; m < 64; m <<= 1) ssl += __shfl_xor(ssl, m, 64);
        const float scale = mrow[i] * __builtin_amdgcn_rcpf(sqrtf(ssl) + 1e-7f);
        #pragma unroll
        for (int u = 0; u < 16; ++u) wacc[u] = fmaf(scale, p[u], wacc[u]);
    }

    float* pr = pbuf + ((size_t)((ic * 16 + b) * H_ + h) << 10) + lane;
    #pragma unroll
    for (int u = 0; u < 16; ++u) pr[u * 64] = wacc[u];
}

// ---------------------------------------------------------------------------
// K3a: fused partial-reduce + weighted row-sum of x.
// grid = 128 (b, jc of 128 j), block = 256 (f).
// ws_[h][j] = sum_ic pbuf[ic][b][h][j0+j]; then
// ypart[b,jc,h,f] = sum_j ws_[h][j] * x[b,j0+j,f]  (all 4 heads per x load)
// ---------------------------------------------------------------------------
__global__ __launch_bounds__(256) void ypart_kernel(
    const float* __restrict__ x, const float* __restrict__ pbuf,
    float* __restrict__ ypart)
{
    const int tid = threadIdx.x;         // f
    const int bx  = blockIdx.x;
    const int b   = bx >> 3;
    const int jc  = bx & 7;
    const int j0  = jc * 128;

    __shared__ float ws_[H_][128];
    #pragma unroll
    for (int t = tid; t < 512; t += 256) {
        const int hh = t >> 7, j = t & 127;
        float s = 0.f;
        for (int ic = 0; ic < 32; ++ic)
            s += pbuf[((size_t)((ic * 16 + b) * H_ + hh) << 10) + j0 + j];
        ws_[hh][j] = s;
    }
    __syncthreads();

    float acc0 = 0.f, acc1 = 0.f, acc2 = 0.f, acc3 = 0.f;
    const float* xcol = x + ((size_t)(b * N_ + j0)) * F_ + tid;
    #pragma unroll 4
    for (int j = 0; j < 128; ++j) {
        const float xv = xcol[(size_t)j * F_];
        acc0 = fmaf(ws_[0][j], xv, acc0);
        acc1 = fmaf(ws_[1][j], xv, acc1);
        acc2 = fmaf(ws_[2][j], xv, acc2);
        acc3 = fmaf(ws_[3][j], xv, acc3);
    }
    float* yp = ypart + (size_t)bx * 4 * F_ + tid;
    yp[0 * F_] = acc0; yp[1 * F_] = acc1; yp[2 * F_] = acc2; yp[3 * F_] = acc3;
}

// ---------------------------------------------------------------------------
// K3b: out[b, h*128+v] = sum_f (sum_jc ypart[b,jc,h,f]) * Wv[h,f,v]
// grid = 64 (b*4+h), block = 256
// ---------------------------------------------------------------------------
__global__ __launch_bounds__(256) void pool_kernel(
    const float* __restrict__ ypart, const float* __restrict__ Wv,
    float* __restrict__ out)
{
    const int tid = threadIdx.x;
    const int bh  = blockIdx.x;
    const int b   = bh >> 2;
    const int h   = bh & 3;
    __shared__ float ys[256];
    float s = 0.f;
    #pragma unroll
    for (int jc = 0; jc < 8; ++jc)
        s += ypart[(size_t)((b * 8 + jc) * H_ + h) * F_ + tid];
    ys[tid] = s;
    __syncthreads();
    if (tid < 128) {
        float acc = 0.f;
        const float* wv = Wv + h * (F_ * 128) + tid;
        #pragma unroll 4
        for (int f = 0; f < F_; ++f) acc = fmaf(ys[f], wv[f * 128], acc);
        out[bh * 128 + tid] = acc;
    }
}

extern "C" void kernel_launch(void* const* d_in, const int* in_sizes, int n_in,
                              void* d_out, int out_size, void* d_ws, size_t ws_size,
                              hipStream_t stream) {
    const float* e    = (const float*)d_in[0];
    const float* x    = (const float*)d_in[1];
    const float* mask = (const float*)d_in[2];
    const float* eps  = (const float*)d_in[3];
    const float* Wq   = (const float*)d_in[4];
    const float* Wk   = (const float*)d_in[5];
    const float* Wv   = (const float*)d_in[6];
    const float* aq   = (const float*)d_in[7];
    const float* bq   = (const float*)d_in[8];
    const float* ak   = (const float*)d_in[9];
    const float* bk   = (const float*)d_in[10];

    float* qbuf  = (float*)d_ws;              // [B,H,N]          65536 f32
    float* kbuf  = qbuf + 65536;              // [B,H,N]          65536 f32
    float* pbuf  = kbuf + 65536;              // [32,B,H,N]     2097152 f32 (8 MB)
    float* ypart = pbuf + 2097152;            // [B,8,H,F]       131072 f32
    float* outf  = (float*)d_out;

    qk_kernel<<<dim3(512, 2), 256, 0, stream>>>(x, Wq, aq, bq, Wk, ak, bk, qbuf, kbuf);
    attn_kernel<<<dim3(32, 16), 256, 0, stream>>>(e, qbuf, kbuf, mask, eps, pbuf);
    ypart_kernel<<<128, 256, 0, stream>>>(x, pbuf, ypart);
    pool_kernel<<<64, 256, 0, stream>>>(ypart, Wv, outf);
}

// Round 3
// 98.517 us; speedup vs baseline: 4.7635x; 1.9701x over previous
//
#include <hip/hip_runtime.h>

#define B_ 16
#define N_ 1024
#define F_ 256
#define H_ 4
#define QDIM 128

typedef __attribute__((ext_vector_type(8))) short bf16x8;
typedef __attribute__((ext_vector_type(4))) float f32x4;

__device__ __forceinline__ float leaky(float x) {
    return x >= 0.f ? x : 0.2f * x;
}

__device__ __forceinline__ float tanh_fast(float x) {
    float e2 = __expf(2.f * x);
    return 1.f - 2.f * __builtin_amdgcn_rcpf(e2 + 1.f);
}

// f32 -> bf16 bits, round-to-nearest-even
__device__ __forceinline__ unsigned short bfbits(float f) {
    unsigned u = __float_as_uint(f);
    return (unsigned short)((u + 0x7fffu + ((u >> 16) & 1u)) >> 16);
}

// ---------------------------------------------------------------------------
// K0a: x (f32) -> xh (bf16), 8 elems/thread
// ---------------------------------------------------------------------------
__global__ __launch_bounds__(256) void convert_x(
    const float4* __restrict__ x4, ushort4* __restrict__ xh4)
{
    const int t = blockIdx.x * 256 + threadIdx.x;     // 524288 threads
    const float4 a = x4[2 * t], b = x4[2 * t + 1];
    ushort4 o0, o1;
    o0.x = bfbits(a.x); o0.y = bfbits(a.y); o0.z = bfbits(a.z); o0.w = bfbits(a.w);
    o1.x = bfbits(b.x); o1.y = bfbits(b.y); o1.z = bfbits(b.z); o1.w = bfbits(b.w);
    xh4[2 * t] = o0; xh4[2 * t + 1] = o1;
}

// ---------------------------------------------------------------------------
// K0b: Wq/Wk [h][f][q] f32 -> Wqt/Wkt [h][q][f] bf16 (transposed for B-frags)
// ---------------------------------------------------------------------------
__global__ __launch_bounds__(256) void convert_w(
    const float* __restrict__ Wq, const float* __restrict__ Wk,
    ushort* __restrict__ Wqt, ushort* __restrict__ Wkt)
{
    const int t = blockIdx.x * 256 + threadIdx.x;     // 0..131071
    const int f = t & 255, q = (t >> 8) & 127, h = t >> 15;
    const float* W = blockIdx.y ? Wk : Wq;
    ushort* O = blockIdx.y ? Wkt : Wqt;
    O[t] = bfbits(W[(h * 256 + f) * 128 + q]);
}

// ---------------------------------------------------------------------------
// K1: MFMA q/k projection. grid (256 m-tiles, 4 heads, 2 {q,k}), block 256.
// Block: 64 rows x 128 cols (one head). Wave w owns cols [w*32, w*32+32).
// A tile (64x256 bf16) in LDS, chunk-XOR swizzled; B in 64 VGPRs/wave.
// Epilogue fuses leaky -> dot(a) -> row reduce -> q/k scalar.
// ---------------------------------------------------------------------------
__global__ __launch_bounds__(256) void qk_mfma(
    const ushort* __restrict__ xh,
    const ushort* __restrict__ Wqt, const ushort* __restrict__ Wkt,
    const float* __restrict__ aq, const float* __restrict__ bq,
    const float* __restrict__ ak, const float* __restrict__ bk,
    float* __restrict__ qbuf, float* __restrict__ kbuf)
{
    const int tid = threadIdx.x;
    const int mt  = blockIdx.x;
    const int h   = blockIdx.y;
    const bool isQ = (blockIdx.z == 0);
    const ushort* Wt = isQ ? Wqt : Wkt;
    const float*  av = isQ ? aq : ak;
    const float*  bv = isQ ? bq : bk;
    float* out = isQ ? qbuf : kbuf;

    __shared__ char  xs[64 * 512];       // 64 rows x 256 bf16 (swizzled)
    __shared__ float sp[4][64];

    // stage A tile: thread t -> row r = t>>2, 16B chunks c = (t&3)+4i
    {
        const int r = tid >> 2;
        const uint4* src = reinterpret_cast<const uint4*>(xh + (size_t)(mt * 64 + r) * 256);
        #pragma unroll
        for (int i = 0; i < 8; ++i) {
            const int c = (tid & 3) + 4 * i;
            const uint4 v = src[c];
            *reinterpret_cast<uint4*>(xs + r * 512 + ((c ^ (r & 7)) << 4)) = v;
        }
    }
    __syncthreads();

    const int l  = tid & 63, w = tid >> 6;
    const int g  = l >> 4, li = l & 15;

    // preload B fragments: B[k = s*32 + 8g + j][col = w*32 + nf*16 + li]
    bf16x8 Bf[8][2];
    #pragma unroll
    for (int nf = 0; nf < 2; ++nf) {
        const int c = w * 32 + nf * 16 + li;
        const ushort* bp = Wt + ((size_t)(h * 128 + c)) * 256 + 8 * g;
        #pragma unroll
        for (int s = 0; s < 8; ++s)
            Bf[s][nf] = *reinterpret_cast<const bf16x8*>(bp + s * 32);
    }

    f32x4 acc[4][2];
    #pragma unroll
    for (int m = 0; m < 4; ++m)
        #pragma unroll
        for (int nf = 0; nf < 2; ++nf)
            acc[m][nf] = (f32x4){0.f, 0.f, 0.f, 0.f};

    #pragma unroll
    for (int s = 0; s < 8; ++s) {
        #pragma unroll
        for (int m = 0; m < 4; ++m) {
            const int r = m * 16 + li;                 // A row
            const int chunk = (4 * s + g) ^ (r & 7);   // swizzled 16B chunk
            const bf16x8 af = *reinterpret_cast<const bf16x8*>(xs + r * 512 + chunk * 16);
            acc[m][0] = __builtin_amdgcn_mfma_f32_16x16x32_bf16(af, Bf[s][0], acc[m][0], 0, 0, 0);
            acc[m][1] = __builtin_amdgcn_mfma_f32_16x16x32_bf16(af, Bf[s][1], acc[m][1], 0, 0, 0);
        }
    }

    // epilogue: part[m][j] = sum over this lane's 2 cols of a[col]*leaky(acc)
    float part[4][4];
    #pragma unroll
    for (int m = 0; m < 4; ++m)
        #pragma unroll
        for (int j = 0; j < 4; ++j) part[m][j] = 0.f;

    #pragma unroll
    for (int nf = 0; nf < 2; ++nf) {
        const float a_ = av[h * QDIM + w * 32 + nf * 16 + li];
        #pragma unroll
        for (int m = 0; m < 4; ++m)
            #pragma unroll
            for (int j = 0; j < 4; ++j)
                part[m][j] = fmaf(a_, leaky(acc[m][nf][j]), part[m][j]);
    }
    #pragma unroll
    for (int mask = 1; mask < 16; mask <<= 1)
        #pragma unroll
        for (int m = 0; m < 4; ++m)
            #pragma unroll
            for (int j = 0; j < 4; ++j)
                part[m][j] += __shfl_xor(part[m][j], mask, 64);

    if (li == 0) {
        #pragma unroll
        for (int m = 0; m < 4; ++m)
            #pragma unroll
            for (int j = 0; j < 4; ++j)
                sp[w][m * 16 + g * 4 + j] = part[m][j];
    }
    __syncthreads();

    if (tid < 64) {
        const float val = sp[0][tid] + sp[1][tid] + sp[2][tid] + sp[3][tid] + bv[h];
        const int R = mt * 64 + tid;
        out[((R >> 10) * H_ + h) * N_ + (R & 1023)] = val;
    }
}

// ---------------------------------------------------------------------------
// K2: scores + row-norm + masked column partial-sums. One pass over e.
// grid = (32 i-chunks of 32, B), block = 256. Wave = head.
// Lane owns j = {lane + 64u}; diagonal's u-slot is block-uniform.
// ---------------------------------------------------------------------------
__global__ __launch_bounds__(256) void attn_kernel(
    const float* __restrict__ e,
    const float* __restrict__ qbuf, const float* __restrict__ kbuf,
    const float* __restrict__ mask, const float* __restrict__ epsp,
    float* __restrict__ pbuf)
{
    const int tid  = threadIdx.x;
    const int h    = tid >> 6;
    const int lane = tid & 63;
    const int b    = blockIdx.y;
    const int ic   = blockIdx.x;
    const int i0   = ic * 32;
    const float epsv = epsp[0];
    const int udiag = ic >> 1;

    const float* kr = kbuf + (b * H_ + h) * N_ + lane;
    float kk[16];
    #pragma unroll
    for (int u = 0; u < 16; ++u) kk[u] = kr[u * 64];

    float wacc[16];
    #pragma unroll
    for (int u = 0; u < 16; ++u) wacc[u] = 0.f;

    const float* qrow  = qbuf + (b * H_ + h) * N_;
    const float* mrow  = mask + b * N_;
    const float* ebase = e + ((size_t)b << 20) + lane;

    #pragma unroll 2
    for (int ii = 0; ii < 32; ++ii) {
        const int i = i0 + ii;
        const float qi = qrow[i];
        const float* er = ebase + ((size_t)i << 10);
        const bool isdl = (lane == (i & 63));
        float p[16];
        float ssl = 0.f;
        #pragma unroll
        for (int u = 0; u < 16; ++u) {
            float ev = er[u * 64];
            if (u == udiag) ev += isdl ? epsv : 0.f;
            p[u] = tanh_fast((qi + kk[u]) * ev);
            ssl = fmaf(p[u], p[u], ssl);
        }
        #pragma unroll
        for (int m = 1; m < 64; m <<= 1) ssl += __shfl_xor(ssl, m, 64);
        const float scale = mrow[i] * __builtin_amdgcn_rcpf(sqrtf(ssl) + 1e-7f);
        #pragma unroll
        for (int u = 0; u < 16; ++u) wacc[u] = fmaf(scale, p[u], wacc[u]);
    }

    float* pr = pbuf + ((size_t)((ic * 16 + b) * H_ + h) << 10) + lane;
    #pragma unroll
    for (int u = 0; u < 16; ++u) pr[u * 64] = wacc[u];
}

// ---------------------------------------------------------------------------
// K3a: partial-reduce + weighted row-sum of x. grid 128 (b, jc), block 256.
// ---------------------------------------------------------------------------
__global__ __launch_bounds__(256) void ypart_kernel(
    const float* __restrict__ x, const float* __restrict__ pbuf,
    float* __restrict__ ypart)
{
    const int tid = threadIdx.x;
    const int bx  = blockIdx.x;
    const int b   = bx >> 3;
    const int jc  = bx & 7;
    const int j0  = jc * 128;

    __shared__ float ws_[H_][128];
    #pragma unroll
    for (int t = tid; t < 512; t += 256) {
        const int hh = t >> 7, j = t & 127;
        float s = 0.f;
        for (int ic = 0; ic < 32; ++ic)
            s += pbuf[((size_t)((ic * 16 + b) * H_ + hh) << 10) + j0 + j];
        ws_[hh][j] = s;
    }
    __syncthreads();

    float acc0 = 0.f, acc1 = 0.f, acc2 = 0.f, acc3 = 0.f;
    const float* xcol = x + ((size_t)(b * N_ + j0)) * F_ + tid;
    #pragma unroll 4
    for (int j = 0; j < 128; ++j) {
        const float xv = xcol[(size_t)j * F_];
        acc0 = fmaf(ws_[0][j], xv, acc0);
        acc1 = fmaf(ws_[1][j], xv, acc1);
        acc2 = fmaf(ws_[2][j], xv, acc2);
        acc3 = fmaf(ws_[3][j], xv, acc3);
    }
    float* yp = ypart + (size_t)bx * 4 * F_ + tid;
    yp[0 * F_] = acc0; yp[1 * F_] = acc1; yp[2 * F_] = acc2; yp[3 * F_] = acc3;
}

// ---------------------------------------------------------------------------
// K3b: out[b, h*128+v] = sum_f (sum_jc ypart[b,jc,h,f]) * Wv[h,f,v]
// ---------------------------------------------------------------------------
__global__ __launch_bounds__(256) void pool_kernel(
    const float* __restrict__ ypart, const float* __restrict__ Wv,
    float* __restrict__ out)
{
    const int tid = threadIdx.x;
    const int bh  = blockIdx.x;
    const int b   = bh >> 2;
    const int h   = bh & 3;
    __shared__ float ys[256];
    float s = 0.f;
    #pragma unroll
    for (int jc = 0; jc < 8; ++jc)
        s += ypart[(size_t)((b * 8 + jc) * H_ + h) * F_ + tid];
    ys[tid] = s;
    __syncthreads();
    if (tid < 128) {
        float acc = 0.f;
        const float* wv = Wv + h * (F_ * 128) + tid;
        #pragma unroll 4
        for (int f = 0; f < F_; ++f) acc = fmaf(ys[f], wv[f * 128], acc);
        out[bh * 128 + tid] = acc;
    }
}

extern "C" void kernel_launch(void* const* d_in, const int* in_sizes, int n_in,
                              void* d_out, int out_size, void* d_ws, size_t ws_size,
                              hipStream_t stream) {
    const float* e    = (const float*)d_in[0];
    const float* x    = (const float*)d_in[1];
    const float* mask = (const float*)d_in[2];
    const float* eps  = (const float*)d_in[3];
    const float* Wq   = (const float*)d_in[4];
    const float* Wk   = (const float*)d_in[5];
    const float* Wv   = (const float*)d_in[6];
    const float* aq   = (const float*)d_in[7];
    const float* bq   = (const float*)d_in[8];
    const float* ak   = (const float*)d_in[9];
    const float* bk   = (const float*)d_in[10];

    float*  qbuf  = (float*)d_ws;             // [B,H,N]        65536 f32
    float*  kbuf  = qbuf + 65536;             // [B,H,N]        65536 f32
    float*  pbuf  = kbuf + 65536;             // [32,B,H,N]   2097152 f32
    float*  ypart = pbuf + 2097152;           // [B,8,H,F]     131072 f32
    ushort* xh    = (ushort*)(ypart + 131072);// [B*N,F] bf16 4194304
    ushort* Wqt   = xh + 4194304;             // [H,Q,F] bf16  131072
    ushort* Wkt   = Wqt + 131072;             // [H,Q,F] bf16  131072
    float*  outf  = (float*)d_out;

    convert_x<<<2048, 256, 0, stream>>>((const float4*)x, (ushort4*)xh);
    convert_w<<<dim3(512, 2), 256, 0, stream>>>(Wq, Wk, Wqt, Wkt);
    qk_mfma<<<dim3(256, 4, 2), 256, 0, stream>>>(xh, Wqt, Wkt, aq, bq, ak, bk, qbuf, kbuf);
    attn_kernel<<<dim3(32, 16), 256, 0, stream>>>(e, qbuf, kbuf, mask, eps, pbuf);
    ypart_kernel<<<128, 256, 0, stream>>>(x, pbuf, ypart);
    pool_kernel<<<64, 256, 0, stream>>>(ypart, Wv, outf);
}

// Round 4
// 92.090 us; speedup vs baseline: 5.0960x; 1.0698x over previous
//
#include <hip/hip_runtime.h>

#define B_ 16
#define N_ 1024
#define F_ 256
#define H_ 4
#define QDIM 128

// 2*log2(e): folded into q,k so tanh arg feeds v_exp_f32 (exp2) directly
#define TANH_PRESCALE 2.8853900817779268f

typedef __attribute__((ext_vector_type(8))) short bf16x8;
typedef __attribute__((ext_vector_type(4))) float f32x4;

__device__ __forceinline__ float leaky(float x) {
    return x >= 0.f ? x : 0.2f * x;
}

// f32 -> bf16 bits, round-to-nearest-even
__device__ __forceinline__ unsigned short bfbits(float f) {
    unsigned u = __float_as_uint(f);
    return (unsigned short)((u + 0x7fffu + ((u >> 16) & 1u)) >> 16);
}

// ---------------------------------------------------------------------------
// K0a: x (f32) -> xh (bf16), 8 elems/thread
// ---------------------------------------------------------------------------
__global__ __launch_bounds__(256) void convert_x(
    const float4* __restrict__ x4, ushort4* __restrict__ xh4)
{
    const int t = blockIdx.x * 256 + threadIdx.x;     // 524288 threads
    const float4 a = x4[2 * t], b = x4[2 * t + 1];
    ushort4 o0, o1;
    o0.x = bfbits(a.x); o0.y = bfbits(a.y); o0.z = bfbits(a.z); o0.w = bfbits(a.w);
    o1.x = bfbits(b.x); o1.y = bfbits(b.y); o1.z = bfbits(b.z); o1.w = bfbits(b.w);
    xh4[2 * t] = o0; xh4[2 * t + 1] = o1;
}

// ---------------------------------------------------------------------------
// K0b: Wq/Wk [h][f][q] f32 -> Wqt/Wkt [h][q][f] bf16 (transposed for B-frags)
// ---------------------------------------------------------------------------
__global__ __launch_bounds__(256) void convert_w(
    const float* __restrict__ Wq, const float* __restrict__ Wk,
    ushort* __restrict__ Wqt, ushort* __restrict__ Wkt)
{
    const int t = blockIdx.x * 256 + threadIdx.x;     // 0..131071
    const int f = t & 255, q = (t >> 8) & 127, h = t >> 15;
    const float* W = blockIdx.y ? Wk : Wq;
    ushort* O = blockIdx.y ? Wkt : Wqt;
    O[t] = bfbits(W[(h * 256 + f) * 128 + q]);
}

// ---------------------------------------------------------------------------
// K1: MFMA q/k projection. grid (256 m-tiles, 4 heads, 2 {q,k}), block 256.
// Epilogue fuses leaky -> dot(a) -> row reduce -> scalar, pre-scaled by
// TANH_PRESCALE so attn's exp arg is exp2-ready.
// ---------------------------------------------------------------------------
__global__ __launch_bounds__(256) void qk_mfma(
    const ushort* __restrict__ xh,
    const ushort* __restrict__ Wqt, const ushort* __restrict__ Wkt,
    const float* __restrict__ aq, const float* __restrict__ bq,
    const float* __restrict__ ak, const float* __restrict__ bk,
    float* __restrict__ qbuf, float* __restrict__ kbuf)
{
    const int tid = threadIdx.x;
    const int mt  = blockIdx.x;
    const int h   = blockIdx.y;
    const bool isQ = (blockIdx.z == 0);
    const ushort* Wt = isQ ? Wqt : Wkt;
    const float*  av = isQ ? aq : ak;
    const float*  bv = isQ ? bq : bk;
    float* out = isQ ? qbuf : kbuf;

    __shared__ char  xs[64 * 512];       // 64 rows x 256 bf16 (swizzled)
    __shared__ float sp[4][64];

    {
        const int r = tid >> 2;
        const uint4* src = reinterpret_cast<const uint4*>(xh + (size_t)(mt * 64 + r) * 256);
        #pragma unroll
        for (int i = 0; i < 8; ++i) {
            const int c = (tid & 3) + 4 * i;
            const uint4 v = src[c];
            *reinterpret_cast<uint4*>(xs + r * 512 + ((c ^ (r & 7)) << 4)) = v;
        }
    }
    __syncthreads();

    const int l  = tid & 63, w = tid >> 6;
    const int g  = l >> 4, li = l & 15;

    bf16x8 Bf[8][2];
    #pragma unroll
    for (int nf = 0; nf < 2; ++nf) {
        const int c = w * 32 + nf * 16 + li;
        const ushort* bp = Wt + ((size_t)(h * 128 + c)) * 256 + 8 * g;
        #pragma unroll
        for (int s = 0; s < 8; ++s)
            Bf[s][nf] = *reinterpret_cast<const bf16x8*>(bp + s * 32);
    }

    f32x4 acc[4][2];
    #pragma unroll
    for (int m = 0; m < 4; ++m)
        #pragma unroll
        for (int nf = 0; nf < 2; ++nf)
            acc[m][nf] = (f32x4){0.f, 0.f, 0.f, 0.f};

    #pragma unroll
    for (int s = 0; s < 8; ++s) {
        #pragma unroll
        for (int m = 0; m < 4; ++m) {
            const int r = m * 16 + li;
            const int chunk = (4 * s + g) ^ (r & 7);
            const bf16x8 af = *reinterpret_cast<const bf16x8*>(xs + r * 512 + chunk * 16);
            acc[m][0] = __builtin_amdgcn_mfma_f32_16x16x32_bf16(af, Bf[s][0], acc[m][0], 0, 0, 0);
            acc[m][1] = __builtin_amdgcn_mfma_f32_16x16x32_bf16(af, Bf[s][1], acc[m][1], 0, 0, 0);
        }
    }

    float part[4][4];
    #pragma unroll
    for (int m = 0; m < 4; ++m)
        #pragma unroll
        for (int j = 0; j < 4; ++j) part[m][j] = 0.f;

    #pragma unroll
    for (int nf = 0; nf < 2; ++nf) {
        const float a_ = av[h * QDIM + w * 32 + nf * 16 + li];
        #pragma unroll
        for (int m = 0; m < 4; ++m)
            #pragma unroll
            for (int j = 0; j < 4; ++j)
                part[m][j] = fmaf(a_, leaky(acc[m][nf][j]), part[m][j]);
    }
    #pragma unroll
    for (int mask = 1; mask < 16; mask <<= 1)
        #pragma unroll
        for (int m = 0; m < 4; ++m)
            #pragma unroll
            for (int j = 0; j < 4; ++j)
                part[m][j] += __shfl_xor(part[m][j], mask, 64);

    if (li == 0) {
        #pragma unroll
        for (int m = 0; m < 4; ++m)
            #pragma unroll
            for (int j = 0; j < 4; ++j)
                sp[w][m * 16 + g * 4 + j] = part[m][j];
    }
    __syncthreads();

    if (tid < 64) {
        const float val = (sp[0][tid] + sp[1][tid] + sp[2][tid] + sp[3][tid] + bv[h]) * TANH_PRESCALE;
        const int R = mt * 64 + tid;
        out[((R >> 10) * H_ + h) * N_ + (R & 1023)] = val;
    }
}

// ---------------------------------------------------------------------------
// K2: scores + row-norm + masked column partial-sums. One pass over e.
// grid = (32 i-chunks of 32, B), block = 512 (8 waves).
// wave = (half, head): head h = wave&3 processes rows [i0+half*16, +16).
// q,k are pre-scaled by 2*log2(e): tanh = 1 - 2*rcp(exp2((q'+k')*e)+1).
// Halves merge wacc via LDS; partials to pbuf[ic][b][h][j] (no atomics).
// ---------------------------------------------------------------------------
__global__ __launch_bounds__(512) void attn_kernel(
    const float* __restrict__ e,
    const float* __restrict__ qbuf, const float* __restrict__ kbuf,
    const float* __restrict__ mask, const float* __restrict__ epsp,
    float* __restrict__ pbuf)
{
    const int tid  = threadIdx.x;
    const int wav  = tid >> 6;
    const int h    = wav & 3;
    const int half = wav >> 2;
    const int lane = tid & 63;
    const int b    = blockIdx.y;
    const int ic   = blockIdx.x;
    const int i0   = ic * 32 + half * 16;
    const float epsv = epsp[0] * TANH_PRESCALE; // e's diagonal bump, same fold
    const int udiag = i0 >> 6;                  // constant across the 16 rows

    __shared__ float red[4][16][64];

    const float* kr = kbuf + (b * H_ + h) * N_ + lane;
    float kk[16];
    #pragma unroll
    for (int u = 0; u < 16; ++u) kk[u] = kr[u * 64];

    float wacc[16];
    #pragma unroll
    for (int u = 0; u < 16; ++u) wacc[u] = 0.f;

    const float* qrow  = qbuf + (b * H_ + h) * N_;
    const float* mrow  = mask + b * N_;
    const float* ebase = e + ((size_t)b << 20) + lane;

    #pragma unroll 2
    for (int ii = 0; ii < 16; ++ii) {
        const int i = i0 + ii;
        const float qi = qrow[i];
        const float* er = ebase + ((size_t)i << 10);
        const bool isdl = (lane == (i & 63));
        const float dadd = isdl ? epsv : 0.f;
        float p[16];
        float ssl = 0.f;
        #pragma unroll
        for (int u = 0; u < 16; ++u) {
            float ev = er[u * 64];
            // diagonal: arg = (q'+k')*e + (q+k)*eps*C ; since eps sits on e,
            // arg = (q'+k')*(e+eps) -> add (q'+k')*dadd
            const float qk = qi + kk[u];
            float arg = qk * ev;
            if (u == udiag) arg = fmaf(qk, dadd, arg);
            const float e2 = __builtin_amdgcn_exp2f(arg);
            const float pv = 1.f - 2.f * __builtin_amdgcn_rcpf(e2 + 1.f);
            p[u] = pv;
            ssl = fmaf(pv, pv, ssl);
        }
        #pragma unroll
        for (int m = 1; m < 64; m <<= 1) ssl += __shfl_xor(ssl, m, 64);
        const float scale = mrow[i] * __builtin_amdgcn_rcpf(sqrtf(ssl) + 1e-7f);
        #pragma unroll
        for (int u = 0; u < 16; ++u) wacc[u] = fmaf(scale, p[u], wacc[u]);
    }

    if (half == 1) {
        #pragma unroll
        for (int u = 0; u < 16; ++u) red[h][u][lane] = wacc[u];
    }
    __syncthreads();
    if (half == 0) {
        float* pr = pbuf + ((size_t)((ic * 16 + b) * H_ + h) << 10) + lane;
        #pragma unroll
        for (int u = 0; u < 16; ++u) pr[u * 64] = wacc[u] + red[h][u][lane];
    }
}

// ---------------------------------------------------------------------------
// K3a: partial-reduce + weighted row-sum of x. grid 128 (b, jc), block 256.
// ---------------------------------------------------------------------------
__global__ __launch_bounds__(256) void ypart_kernel(
    const float* __restrict__ x, const float* __restrict__ pbuf,
    float* __restrict__ ypart)
{
    const int tid = threadIdx.x;
    const int bx  = blockIdx.x;
    const int b   = bx >> 3;
    const int jc  = bx & 7;
    const int j0  = jc * 128;

    __shared__ float ws_[H_][128];
    #pragma unroll
    for (int t = tid; t < 512; t += 256) {
        const int hh = t >> 7, j = t & 127;
        float s = 0.f;
        for (int ic = 0; ic < 32; ++ic)
            s += pbuf[((size_t)((ic * 16 + b) * H_ + hh) << 10) + j0 + j];
        ws_[hh][j] = s;
    }
    __syncthreads();

    float acc0 = 0.f, acc1 = 0.f, acc2 = 0.f, acc3 = 0.f;
    const float* xcol = x + ((size_t)(b * N_ + j0)) * F_ + tid;
    #pragma unroll 4
    for (int j = 0; j < 128; ++j) {
        const float xv = xcol[(size_t)j * F_];
        acc0 = fmaf(ws_[0][j], xv, acc0);
        acc1 = fmaf(ws_[1][j], xv, acc1);
        acc2 = fmaf(ws_[2][j], xv, acc2);
        acc3 = fmaf(ws_[3][j], xv, acc3);
    }
    float* yp = ypart + (size_t)bx * 4 * F_ + tid;
    yp[0 * F_] = acc0; yp[1 * F_] = acc1; yp[2 * F_] = acc2; yp[3 * F_] = acc3;
}

// ---------------------------------------------------------------------------
// K3b: out[b, h*128+v] = sum_f (sum_jc ypart[b,jc,h,f]) * Wv[h,f,v]
// ---------------------------------------------------------------------------
__global__ __launch_bounds__(256) void pool_kernel(
    const float* __restrict__ ypart, const float* __restrict__ Wv,
    float* __restrict__ out)
{
    const int tid = threadIdx.x;
    const int bh  = blockIdx.x;
    const int b   = bh >> 2;
    const int h   = bh & 3;
    __shared__ float ys[256];
    float s = 0.f;
    #pragma unroll
    for (int jc = 0; jc < 8; ++jc)
        s += ypart[(size_t)((b * 8 + jc) * H_ + h) * F_ + tid];
    ys[tid] = s;
    __syncthreads();
    if (tid < 128) {
        float acc = 0.f;
        const float* wv = Wv + h * (F_ * 128) + tid;
        #pragma unroll 4
        for (int f = 0; f < F_; ++f) acc = fmaf(ys[f], wv[f * 128], acc);
        out[bh * 128 + tid] = acc;
    }
}

extern "C" void kernel_launch(void* const* d_in, const int* in_sizes, int n_in,
                              void* d_out, int out_size, void* d_ws, size_t ws_size,
                              hipStream_t stream) {
    const float* e    = (const float*)d_in[0];
    const float* x    = (const float*)d_in[1];
    const float* mask = (const float*)d_in[2];
    const float* eps  = (const float*)d_in[3];
    const float* Wq   = (const float*)d_in[4];
    const float* Wk   = (const float*)d_in[5];
    const float* Wv   = (const float*)d_in[6];
    const float* aq   = (const float*)d_in[7];
    const float* bq   = (const float*)d_in[8];
    const float* ak   = (const float*)d_in[9];
    const float* bk   = (const float*)d_in[10];

    float*  qbuf  = (float*)d_ws;             // [B,H,N]        65536 f32
    float*  kbuf  = qbuf + 65536;             // [B,H,N]        65536 f32
    float*  pbuf  = kbuf + 65536;             // [32,B,H,N]   2097152 f32
    float*  ypart = pbuf + 2097152;           // [B,8,H,F]     131072 f32
    ushort* xh    = (ushort*)(ypart + 131072);// [B*N,F] bf16 4194304
    ushort* Wqt   = xh + 4194304;             // [H,Q,F] bf16  131072
    ushort* Wkt   = Wqt + 131072;             // [H,Q,F] bf16  131072
    float*  outf  = (float*)d_out;

    convert_x<<<2048, 256, 0, stream>>>((const float4*)x, (ushort4*)xh);
    convert_w<<<dim3(512, 2), 256, 0, stream>>>(Wq, Wk, Wqt, Wkt);
    qk_mfma<<<dim3(256, 4, 2), 256, 0, stream>>>(xh, Wqt, Wkt, aq, bq, ak, bk, qbuf, kbuf);
    attn_kernel<<<dim3(32, 16), 512, 0, stream>>>(e, qbuf, kbuf, mask, eps, pbuf);
    ypart_kernel<<<128, 256, 0, stream>>>(x, pbuf, ypart);
    pool_kernel<<<64, 256, 0, stream>>>(ypart, Wv, outf);
}

// Round 5
// 87.517 us; speedup vs baseline: 5.3622x; 1.0523x over previous
//
#include <hip/hip_runtime.h>

#define B_ 16
#define N_ 1024
#define F_ 256
#define H_ 4
#define QDIM 128

// 2*log2(e): folded into q,k so tanh arg feeds v_exp_f32 (exp2) directly
#define TANH_PRESCALE 2.8853900817779268f

typedef __attribute__((ext_vector_type(8))) short bf16x8;
typedef __attribute__((ext_vector_type(4))) float f32x4;

__device__ __forceinline__ float leaky(float x) {
    return x >= 0.f ? x : 0.2f * x;
}

// f32 -> bf16 bits, round-to-nearest-even
__device__ __forceinline__ unsigned short bfbits(float f) {
    unsigned u = __float_as_uint(f);
    return (unsigned short)((u + 0x7fffu + ((u >> 16) & 1u)) >> 16);
}

// ---------------------------------------------------------------------------
// K0: fused converts. blocks [0,2048): x f32->bf16 (8/thread);
//     blocks [2048,3072): Wq/Wk [h][f][q] -> [h][q][f] bf16.
// ---------------------------------------------------------------------------
__global__ __launch_bounds__(256) void convert_all(
    const float4* __restrict__ x4, ushort4* __restrict__ xh4,
    const float* __restrict__ Wq, const float* __restrict__ Wk,
    ushort* __restrict__ Wqt, ushort* __restrict__ Wkt)
{
    const int bx = blockIdx.x;
    if (bx < 2048) {
        const int t = bx * 256 + threadIdx.x;
        const float4 a = x4[2 * t], b = x4[2 * t + 1];
        ushort4 o0, o1;
        o0.x = bfbits(a.x); o0.y = bfbits(a.y); o0.z = bfbits(a.z); o0.w = bfbits(a.w);
        o1.x = bfbits(b.x); o1.y = bfbits(b.y); o1.z = bfbits(b.z); o1.w = bfbits(b.w);
        xh4[2 * t] = o0; xh4[2 * t + 1] = o1;
    } else {
        const int t2 = (bx - 2048) * 256 + threadIdx.x;   // 0..262143
        const int z = t2 >> 17, t = t2 & 131071;
        const int f = t & 255, q = (t >> 8) & 127, h = t >> 15;
        const float* W = z ? Wk : Wq;
        ushort* O = z ? Wkt : Wqt;
        O[t] = bfbits(W[(h * 256 + f) * 128 + q]);
    }
}

// ---------------------------------------------------------------------------
// K1: MFMA q/k projection. grid (256 m-tiles, 4 heads, 2 {q,k}), block 256.
// Epilogue fuses leaky -> dot(a) -> row reduce -> scalar, pre-scaled by
// TANH_PRESCALE so attn's exp arg is exp2-ready.
// ---------------------------------------------------------------------------
__global__ __launch_bounds__(256) void qk_mfma(
    const ushort* __restrict__ xh,
    const ushort* __restrict__ Wqt, const ushort* __restrict__ Wkt,
    const float* __restrict__ aq, const float* __restrict__ bq,
    const float* __restrict__ ak, const float* __restrict__ bk,
    float* __restrict__ qbuf, float* __restrict__ kbuf)
{
    const int tid = threadIdx.x;
    const int mt  = blockIdx.x;
    const int h   = blockIdx.y;
    const bool isQ = (blockIdx.z == 0);
    const ushort* Wt = isQ ? Wqt : Wkt;
    const float*  av = isQ ? aq : ak;
    const float*  bv = isQ ? bq : bk;
    float* out = isQ ? qbuf : kbuf;

    __shared__ char  xs[64 * 512];       // 64 rows x 256 bf16 (swizzled)
    __shared__ float sp[4][64];

    {
        const int r = tid >> 2;
        const uint4* src = reinterpret_cast<const uint4*>(xh + (size_t)(mt * 64 + r) * 256);
        #pragma unroll
        for (int i = 0; i < 8; ++i) {
            const int c = (tid & 3) + 4 * i;
            const uint4 v = src[c];
            *reinterpret_cast<uint4*>(xs + r * 512 + ((c ^ (r & 7)) << 4)) = v;
        }
    }
    __syncthreads();

    const int l  = tid & 63, w = tid >> 6;
    const int g  = l >> 4, li = l & 15;

    bf16x8 Bf[8][2];
    #pragma unroll
    for (int nf = 0; nf < 2; ++nf) {
        const int c = w * 32 + nf * 16 + li;
        const ushort* bp = Wt + ((size_t)(h * 128 + c)) * 256 + 8 * g;
        #pragma unroll
        for (int s = 0; s < 8; ++s)
            Bf[s][nf] = *reinterpret_cast<const bf16x8*>(bp + s * 32);
    }

    f32x4 acc[4][2];
    #pragma unroll
    for (int m = 0; m < 4; ++m)
        #pragma unroll
        for (int nf = 0; nf < 2; ++nf)
            acc[m][nf] = (f32x4){0.f, 0.f, 0.f, 0.f};

    #pragma unroll
    for (int s = 0; s < 8; ++s) {
        #pragma unroll
        for (int m = 0; m < 4; ++m) {
            const int r = m * 16 + li;
            const int chunk = (4 * s + g) ^ (r & 7);
            const bf16x8 af = *reinterpret_cast<const bf16x8*>(xs + r * 512 + chunk * 16);
            acc[m][0] = __builtin_amdgcn_mfma_f32_16x16x32_bf16(af, Bf[s][0], acc[m][0], 0, 0, 0);
            acc[m][1] = __builtin_amdgcn_mfma_f32_16x16x32_bf16(af, Bf[s][1], acc[m][1], 0, 0, 0);
        }
    }

    float part[4][4];
    #pragma unroll
    for (int m = 0; m < 4; ++m)
        #pragma unroll
        for (int j = 0; j < 4; ++j) part[m][j] = 0.f;

    #pragma unroll
    for (int nf = 0; nf < 2; ++nf) {
        const float a_ = av[h * QDIM + w * 32 + nf * 16 + li];
        #pragma unroll
        for (int m = 0; m < 4; ++m)
            #pragma unroll
            for (int j = 0; j < 4; ++j)
                part[m][j] = fmaf(a_, leaky(acc[m][nf][j]), part[m][j]);
    }
    #pragma unroll
    for (int mask = 1; mask < 16; mask <<= 1)
        #pragma unroll
        for (int m = 0; m < 4; ++m)
            #pragma unroll
            for (int j = 0; j < 4; ++j)
                part[m][j] += __shfl_xor(part[m][j], mask, 64);

    if (li == 0) {
        #pragma unroll
        for (int m = 0; m < 4; ++m)
            #pragma unroll
            for (int j = 0; j < 4; ++j)
                sp[w][m * 16 + g * 4 + j] = part[m][j];
    }
    __syncthreads();

    if (tid < 64) {
        const float val = (sp[0][tid] + sp[1][tid] + sp[2][tid] + sp[3][tid] + bv[h]) * TANH_PRESCALE;
        const int R = mt * 64 + tid;
        out[((R >> 10) * H_ + h) * N_ + (R & 1023)] = val;
    }
}

// ---------------------------------------------------------------------------
// K2: scores + row-norm + masked column partial-sums. One pass over e.
// grid = (64 i-chunks of 16, B), block = 512 (8 waves = half x head).
// Lane owns j = u*256 + lane*4 + c (float4 loads/stores).
// q,k pre-scaled by C=2*log2(e); diagonal adds qk*eps (eps RAW -- the C is
// already inside qk). Halves merge via LDS; no atomics.
// ---------------------------------------------------------------------------
__global__ __launch_bounds__(512) void attn_kernel(
    const float* __restrict__ e,
    const float* __restrict__ qbuf, const float* __restrict__ kbuf,
    const float* __restrict__ mask, const float* __restrict__ epsp,
    float* __restrict__ pbuf)
{
    const int tid  = threadIdx.x;
    const int wav  = tid >> 6;
    const int h    = wav & 3;
    const int half = wav >> 2;
    const int lane = tid & 63;
    const int b    = blockIdx.y;
    const int ic   = blockIdx.x;
    const int i0   = ic * 16 + half * 8;
    const float epsv = epsp[0];              // RAW: qk already carries C
    const int udiag = ic >> 4;               // (i>>8), uniform across chunk

    __shared__ f32x4 red4[4][4][64];         // 16 KB

    const f32x4* kr4 = reinterpret_cast<const f32x4*>(kbuf + (b * H_ + h) * N_);
    f32x4 kk4[4];
    #pragma unroll
    for (int u = 0; u < 4; ++u) kk4[u] = kr4[u * 64 + lane];

    f32x4 wacc4[4];
    #pragma unroll
    for (int u = 0; u < 4; ++u) wacc4[u] = (f32x4){0.f, 0.f, 0.f, 0.f};

    const float* qrow  = qbuf + (b * H_ + h) * N_;
    const float* mrow  = mask + b * N_;
    const f32x4* ebase = reinterpret_cast<const f32x4*>(e + ((size_t)b << 20)) + lane;

    #pragma unroll 2
    for (int ii = 0; ii < 8; ++ii) {
        const int i = i0 + ii;
        const float qi = qrow[i];
        const f32x4* er4 = ebase + ((size_t)i << 8);
        const bool isdl = (lane == ((i >> 2) & 63));
        const float dadd = isdl ? epsv : 0.f;
        float p[4][4];
        float ssl = 0.f;
        #pragma unroll
        for (int u = 0; u < 4; ++u) {
            const f32x4 ev = er4[u * 64];
            const f32x4 kv = kk4[u];
            #pragma unroll
            for (int c = 0; c < 4; ++c) {
                const float qk = qi + kv[c];
                float arg = qk * ev[c];
                if (u == udiag && c == (ii & 3)) arg = fmaf(qk, dadd, arg);
                const float e2 = __builtin_amdgcn_exp2f(arg);
                const float pv = 1.f - 2.f * __builtin_amdgcn_rcpf(e2 + 1.f);
                p[u][c] = pv;
                ssl = fmaf(pv, pv, ssl);
            }
        }
        #pragma unroll
        for (int m = 1; m < 64; m <<= 1) ssl += __shfl_xor(ssl, m, 64);
        const float scale = mrow[i] * __builtin_amdgcn_rcpf(sqrtf(ssl) + 1e-7f);
        #pragma unroll
        for (int u = 0; u < 4; ++u)
            #pragma unroll
            for (int c = 0; c < 4; ++c)
                wacc4[u][c] = fmaf(scale, p[u][c], wacc4[u][c]);
    }

    if (half == 1) {
        #pragma unroll
        for (int u = 0; u < 4; ++u) red4[h][u][lane] = wacc4[u];
    }
    __syncthreads();
    if (half == 0) {
        f32x4* pr4 = reinterpret_cast<f32x4*>(pbuf + ((size_t)((ic * 16 + b) * H_ + h) << 10));
        #pragma unroll
        for (int u = 0; u < 4; ++u) {
            const f32x4 o = wacc4[u] + red4[h][u][lane];
            pr4[u * 64 + lane] = o;
        }
    }
}

// ---------------------------------------------------------------------------
// K3a: partial-reduce (64 ic) + weighted row-sum of x.
// grid 256 (b, jc of 64 j), block 256.
// ---------------------------------------------------------------------------
__global__ __launch_bounds__(256) void ypart_kernel(
    const float* __restrict__ x, const float* __restrict__ pbuf,
    float* __restrict__ ypart)
{
    const int tid = threadIdx.x;
    const int bx  = blockIdx.x;
    const int b   = bx >> 4;
    const int jc  = bx & 15;
    const int j0  = jc * 64;

    __shared__ float ws_[H_][64];
    {
        const int hh = tid >> 6, j = tid & 63;   // exactly 256 = 4h x 64j
        const float* pp = pbuf + ((size_t)(b * H_ + hh) << 10) + j0 + j;
        float s0 = 0.f, s1 = 0.f, s2 = 0.f, s3 = 0.f;
        #pragma unroll 4
        for (int ic = 0; ic < 64; ic += 4) {
            s0 += pp[(size_t)(ic + 0) * 65536];
            s1 += pp[(size_t)(ic + 1) * 65536];
            s2 += pp[(size_t)(ic + 2) * 65536];
            s3 += pp[(size_t)(ic + 3) * 65536];
        }
        ws_[hh][j] = (s0 + s1) + (s2 + s3);
    }
    __syncthreads();

    float a0 = 0.f, a1 = 0.f, a2 = 0.f, a3 = 0.f;
    const float* xcol = x + ((size_t)(b * N_ + j0)) * F_ + tid;
    #pragma unroll 4
    for (int j = 0; j < 64; ++j) {
        const float xv = xcol[(size_t)j * F_];
        a0 = fmaf(ws_[0][j], xv, a0);
        a1 = fmaf(ws_[1][j], xv, a1);
        a2 = fmaf(ws_[2][j], xv, a2);
        a3 = fmaf(ws_[3][j], xv, a3);
    }
    float* yp = ypart + (size_t)(b * 16 + jc) * (H_ * F_) + tid;
    yp[0 * F_] = a0; yp[1 * F_] = a1; yp[2 * F_] = a2; yp[3 * F_] = a3;
}

// ---------------------------------------------------------------------------
// K3b: out[b, h*128+v] = sum_f (sum_jc ypart[b,jc,h,f]) * Wv[h,f,v]
// ---------------------------------------------------------------------------
__global__ __launch_bounds__(256) void pool_kernel(
    const float* __restrict__ ypart, const float* __restrict__ Wv,
    float* __restrict__ out)
{
    const int tid = threadIdx.x;
    const int bh  = blockIdx.x;
    const int b   = bh >> 2;
    const int h   = bh & 3;
    __shared__ float ys[256];
    float s = 0.f;
    #pragma unroll
    for (int jc = 0; jc < 16; ++jc)
        s += ypart[(size_t)(b * 16 + jc) * (H_ * F_) + h * F_ + tid];
    ys[tid] = s;
    __syncthreads();
    if (tid < 128) {
        float acc = 0.f;
        const float* wv = Wv + h * (F_ * 128) + tid;
        #pragma unroll 4
        for (int f = 0; f < F_; ++f) acc = fmaf(ys[f], wv[f * 128], acc);
        out[bh * 128 + tid] = acc;
    }
}

extern "C" void kernel_launch(void* const* d_in, const int* in_sizes, int n_in,
                              void* d_out, int out_size, void* d_ws, size_t ws_size,
                              hipStream_t stream) {
    const float* e    = (const float*)d_in[0];
    const float* x    = (const float*)d_in[1];
    const float* mask = (const float*)d_in[2];
    const float* eps  = (const float*)d_in[3];
    const float* Wq   = (const float*)d_in[4];
    const float* Wk   = (const float*)d_in[5];
    const float* Wv   = (const float*)d_in[6];
    const float* aq   = (const float*)d_in[7];
    const float* bq   = (const float*)d_in[8];
    const float* ak   = (const float*)d_in[9];
    const float* bk   = (const float*)d_in[10];

    float*  qbuf  = (float*)d_ws;             // [B,H,N]          65536 f32
    float*  kbuf  = qbuf + 65536;             // [B,H,N]          65536 f32
    float*  pbuf  = kbuf + 65536;             // [64,B,H,N]     4194304 f32 (16.8MB)
    float*  ypart = pbuf + 4194304;           // [B,16,H,F]      262144 f32
    ushort* xh    = (ushort*)(ypart + 262144);// [B*N,F] bf16   4194304
    ushort* Wqt   = xh + 4194304;             // [H,Q,F] bf16    131072
    ushort* Wkt   = Wqt + 131072;             // [H,Q,F] bf16    131072
    float*  outf  = (float*)d_out;

    convert_all<<<3072, 256, 0, stream>>>((const float4*)x, (ushort4*)xh, Wq, Wk, Wqt, Wkt);
    qk_mfma<<<dim3(256, 4, 2), 256, 0, stream>>>(xh, Wqt, Wkt, aq, bq, ak, bk, qbuf, kbuf);
    attn_kernel<<<dim3(64, 16), 512, 0, stream>>>(e, qbuf, kbuf, mask, eps, pbuf);
    ypart_kernel<<<256, 256, 0, stream>>>(x, pbuf, ypart);
    pool_kernel<<<64, 256, 0, stream>>>(ypart, Wv, outf);
}

// Round 6
// 83.569 us; speedup vs baseline: 5.6156x; 1.0472x over previous
//
#include <hip/hip_runtime.h>

#define B_ 16
#define N_ 1024
#define F_ 256
#define H_ 4
#define QDIM 128

// 2*log2(e): folded into q,k so tanh arg feeds v_exp_f32 (exp2) directly
#define TANH_PRESCALE 2.8853900817779268f

typedef __attribute__((ext_vector_type(8))) short bf16x8;
typedef __attribute__((ext_vector_type(4))) float f32x4;
typedef __attribute__((ext_vector_type(2))) float f32x2;

__device__ __forceinline__ float leaky(float x) {
    return x >= 0.f ? x : 0.2f * x;
}

// f32 -> bf16 bits, round-to-nearest-even
__device__ __forceinline__ unsigned short bfbits(float f) {
    unsigned u = __float_as_uint(f);
    return (unsigned short)((u + 0x7fffu + ((u >> 16) & 1u)) >> 16);
}

__device__ __forceinline__ float bf2f(unsigned short u) {
    return __uint_as_float(((unsigned)u) << 16);
}

// ---------------------------------------------------------------------------
// K0: fused converts. blocks [0,2048): x f32->bf16 (8/thread);
//     blocks [2048,3072): Wq/Wk [h][f][q] -> [h][q][f] bf16.
// ---------------------------------------------------------------------------
__global__ __launch_bounds__(256) void convert_all(
    const float4* __restrict__ x4, ushort4* __restrict__ xh4,
    const float* __restrict__ Wq, const float* __restrict__ Wk,
    ushort* __restrict__ Wqt, ushort* __restrict__ Wkt)
{
    const int bx = blockIdx.x;
    if (bx < 2048) {
        const int t = bx * 256 + threadIdx.x;
        const float4 a = x4[2 * t], b = x4[2 * t + 1];
        ushort4 o0, o1;
        o0.x = bfbits(a.x); o0.y = bfbits(a.y); o0.z = bfbits(a.z); o0.w = bfbits(a.w);
        o1.x = bfbits(b.x); o1.y = bfbits(b.y); o1.z = bfbits(b.z); o1.w = bfbits(b.w);
        xh4[2 * t] = o0; xh4[2 * t + 1] = o1;
    } else {
        const int t2 = (bx - 2048) * 256 + threadIdx.x;   // 0..262143
        const int z = t2 >> 17, t = t2 & 131071;
        const int f = t & 255, q = (t >> 8) & 127, h = t >> 15;
        const float* W = z ? Wk : Wq;
        ushort* O = z ? Wkt : Wqt;
        O[t] = bfbits(W[(h * 256 + f) * 128 + q]);
    }
}

// ---------------------------------------------------------------------------
// K1: MFMA q/k projection. grid (256 m-tiles, 4 heads, 2 {q,k}), block 256.
// Epilogue fuses leaky -> dot(a) -> row reduce -> scalar, pre-scaled by
// TANH_PRESCALE so attn's exp arg is exp2-ready.
// ---------------------------------------------------------------------------
__global__ __launch_bounds__(256) void qk_mfma(
    const ushort* __restrict__ xh,
    const ushort* __restrict__ Wqt, const ushort* __restrict__ Wkt,
    const float* __restrict__ aq, const float* __restrict__ bq,
    const float* __restrict__ ak, const float* __restrict__ bk,
    float* __restrict__ qbuf, float* __restrict__ kbuf)
{
    const int tid = threadIdx.x;
    const int mt  = blockIdx.x;
    const int h   = blockIdx.y;
    const bool isQ = (blockIdx.z == 0);
    const ushort* Wt = isQ ? Wqt : Wkt;
    const float*  av = isQ ? aq : ak;
    const float*  bv = isQ ? bq : bk;
    float* out = isQ ? qbuf : kbuf;

    __shared__ char  xs[64 * 512];       // 64 rows x 256 bf16 (swizzled)
    __shared__ float sp[4][64];

    {
        const int r = tid >> 2;
        const uint4* src = reinterpret_cast<const uint4*>(xh + (size_t)(mt * 64 + r) * 256);
        #pragma unroll
        for (int i = 0; i < 8; ++i) {
            const int c = (tid & 3) + 4 * i;
            const uint4 v = src[c];
            *reinterpret_cast<uint4*>(xs + r * 512 + ((c ^ (r & 7)) << 4)) = v;
        }
    }
    __syncthreads();

    const int l  = tid & 63, w = tid >> 6;
    const int g  = l >> 4, li = l & 15;

    bf16x8 Bf[8][2];
    #pragma unroll
    for (int nf = 0; nf < 2; ++nf) {
        const int c = w * 32 + nf * 16 + li;
        const ushort* bp = Wt + ((size_t)(h * 128 + c)) * 256 + 8 * g;
        #pragma unroll
        for (int s = 0; s < 8; ++s)
            Bf[s][nf] = *reinterpret_cast<const bf16x8*>(bp + s * 32);
    }

    f32x4 acc[4][2];
    #pragma unroll
    for (int m = 0; m < 4; ++m)
        #pragma unroll
        for (int nf = 0; nf < 2; ++nf)
            acc[m][nf] = (f32x4){0.f, 0.f, 0.f, 0.f};

    #pragma unroll
    for (int s = 0; s < 8; ++s) {
        #pragma unroll
        for (int m = 0; m < 4; ++m) {
            const int r = m * 16 + li;
            const int chunk = (4 * s + g) ^ (r & 7);
            const bf16x8 af = *reinterpret_cast<const bf16x8*>(xs + r * 512 + chunk * 16);
            acc[m][0] = __builtin_amdgcn_mfma_f32_16x16x32_bf16(af, Bf[s][0], acc[m][0], 0, 0, 0);
            acc[m][1] = __builtin_amdgcn_mfma_f32_16x16x32_bf16(af, Bf[s][1], acc[m][1], 0, 0, 0);
        }
    }

    float part[4][4];
    #pragma unroll
    for (int m = 0; m < 4; ++m)
        #pragma unroll
        for (int j = 0; j < 4; ++j) part[m][j] = 0.f;

    #pragma unroll
    for (int nf = 0; nf < 2; ++nf) {
        const float a_ = av[h * QDIM + w * 32 + nf * 16 + li];
        #pragma unroll
        for (int m = 0; m < 4; ++m)
            #pragma unroll
            for (int j = 0; j < 4; ++j)
                part[m][j] = fmaf(a_, leaky(acc[m][nf][j]), part[m][j]);
    }
    #pragma unroll
    for (int mask = 1; mask < 16; mask <<= 1)
        #pragma unroll
        for (int m = 0; m < 4; ++m)
            #pragma unroll
            for (int j = 0; j < 4; ++j)
                part[m][j] += __shfl_xor(part[m][j], mask, 64);

    if (li == 0) {
        #pragma unroll
        for (int m = 0; m < 4; ++m)
            #pragma unroll
            for (int j = 0; j < 4; ++j)
                sp[w][m * 16 + g * 4 + j] = part[m][j];
    }
    __syncthreads();

    if (tid < 64) {
        const float val = (sp[0][tid] + sp[1][tid] + sp[2][tid] + sp[3][tid] + bv[h]) * TANH_PRESCALE;
        const int R = mt * 64 + tid;
        out[((R >> 10) * H_ + h) * N_ + (R & 1023)] = val;
    }
}

// ---------------------------------------------------------------------------
// K2: scores + row-norm + masked column partial-sums. One pass over e.
// grid = (64 i-chunks of 16, B), block = 512 (8 waves = half x head).
// Lane owns j = u*256 + lane*4 + c. Inner math on float2 pairs so LLVM can
// select packed v_pk_add/mul/fma_f32 (trans stays scalar). Partials stored
// bf16 to halve pbuf traffic. No atomics.
// ---------------------------------------------------------------------------
__global__ __launch_bounds__(512) void attn_kernel(
    const float* __restrict__ e,
    const float* __restrict__ qbuf, const float* __restrict__ kbuf,
    const float* __restrict__ mask, const float* __restrict__ epsp,
    ushort* __restrict__ pbuf)
{
    const int tid  = threadIdx.x;
    const int wav  = tid >> 6;
    const int h    = wav & 3;
    const int half = wav >> 2;
    const int lane = tid & 63;
    const int b    = blockIdx.y;
    const int ic   = blockIdx.x;
    const int i0   = ic * 16 + half * 8;
    const float epsv = epsp[0];              // RAW: qk already carries C
    const int udiag = ic >> 4;               // (i>>8), uniform across chunk

    __shared__ f32x2 red2[4][8][64];         // 16 KB

    const f32x4* kr4 = reinterpret_cast<const f32x4*>(kbuf + (b * H_ + h) * N_);
    f32x2 kk2[8];
    #pragma unroll
    for (int u = 0; u < 4; ++u) {
        const f32x4 kv = kr4[u * 64 + lane];
        kk2[2 * u]     = __builtin_shufflevector(kv, kv, 0, 1);
        kk2[2 * u + 1] = __builtin_shufflevector(kv, kv, 2, 3);
    }

    f32x2 wacc2[8];
    #pragma unroll
    for (int p = 0; p < 8; ++p) wacc2[p] = (f32x2){0.f, 0.f};

    const float* qrow  = qbuf + (b * H_ + h) * N_;
    const float* mrow  = mask + b * N_;
    const f32x4* ebase = reinterpret_cast<const f32x4*>(e + ((size_t)b << 20)) + lane;

    const f32x2 one2 = {1.f, 1.f};
    const f32x2 m2   = {-2.f, -2.f};

    #pragma unroll 2
    for (int ii = 0; ii < 8; ++ii) {
        const int i = i0 + ii;
        const float qi = qrow[i];
        const f32x2 qi2 = {qi, qi};
        const f32x4* er4 = ebase + ((size_t)i << 8);
        const bool isdl = (lane == ((i >> 2) & 63));
        const float dadd = isdl ? epsv : 0.f;
        f32x2 pv[8];
        f32x2 sslv = {0.f, 0.f};
        #pragma unroll
        for (int u = 0; u < 4; ++u) {
            const f32x4 ev = er4[u * 64];
            #pragma unroll
            for (int s = 0; s < 2; ++s) {
                const int p = 2 * u + s;
                const f32x2 ev2 = s ? __builtin_shufflevector(ev, ev, 2, 3)
                                    : __builtin_shufflevector(ev, ev, 0, 1);
                const f32x2 qk2 = qi2 + kk2[p];            // v_pk_add
                f32x2 arg2 = qk2 * ev2;                    // v_pk_mul
                if (u == udiag && s == ((ii & 3) >> 1)) {  // compile-time comp
                    const int cc = ii & 1;
                    arg2[cc] = fmaf(qk2[cc], dadd, arg2[cc]);
                }
                f32x2 ex;
                ex[0] = __builtin_amdgcn_exp2f(arg2[0]);
                ex[1] = __builtin_amdgcn_exp2f(arg2[1]);
                const f32x2 d2 = ex + one2;                // v_pk_add
                f32x2 r2;
                r2[0] = __builtin_amdgcn_rcpf(d2[0]);
                r2[1] = __builtin_amdgcn_rcpf(d2[1]);
                const f32x2 pvv = __builtin_elementwise_fma(r2, m2, one2); // v_pk_fma
                pv[p] = pvv;
                sslv = __builtin_elementwise_fma(pvv, pvv, sslv);          // v_pk_fma
            }
        }
        float ssl = sslv[0] + sslv[1];
        #pragma unroll
        for (int m = 1; m < 64; m <<= 1) ssl += __shfl_xor(ssl, m, 64);
        const float scale = mrow[i] * __builtin_amdgcn_rcpf(sqrtf(ssl) + 1e-7f);
        const f32x2 sc2 = {scale, scale};
        #pragma unroll
        for (int p = 0; p < 8; ++p)
            wacc2[p] = __builtin_elementwise_fma(sc2, pv[p], wacc2[p]);    // v_pk_fma
    }

    if (half == 1) {
        #pragma unroll
        for (int p = 0; p < 8; ++p) red2[h][p][lane] = wacc2[p];
    }
    __syncthreads();
    if (half == 0) {
        ushort* pr = pbuf + ((size_t)((ic * 16 + b) * H_ + h) << 10);
        #pragma unroll
        for (int u = 0; u < 4; ++u) {
            const f32x2 a = wacc2[2 * u]     + red2[h][2 * u][lane];
            const f32x2 c = wacc2[2 * u + 1] + red2[h][2 * u + 1][lane];
            ushort4 o;
            o.x = bfbits(a[0]); o.y = bfbits(a[1]);
            o.z = bfbits(c[0]); o.w = bfbits(c[1]);
            *reinterpret_cast<ushort4*>(pr + u * 256 + lane * 4) = o;
        }
    }
}

// ---------------------------------------------------------------------------
// K3a: partial-reduce (64 ic, bf16) + weighted row-sum of xh (bf16).
// grid 256 (b, jc of 64 j), block 256.
// ---------------------------------------------------------------------------
__global__ __launch_bounds__(256) void ypart_kernel(
    const ushort* __restrict__ xh, const ushort* __restrict__ pbuf,
    float* __restrict__ ypart)
{
    const int tid = threadIdx.x;
    const int bx  = blockIdx.x;
    const int b   = bx >> 4;
    const int jc  = bx & 15;
    const int j0  = jc * 64;

    __shared__ float ws_[H_][64];
    {
        const int hh = tid >> 6, j = tid & 63;   // exactly 256 = 4h x 64j
        const ushort* pp = pbuf + ((size_t)(b * H_ + hh) << 10) + j0 + j;
        float s0 = 0.f, s1 = 0.f, s2 = 0.f, s3 = 0.f;
        #pragma unroll 4
        for (int ic = 0; ic < 64; ic += 4) {
            s0 += bf2f(pp[(size_t)(ic + 0) * 65536]);
            s1 += bf2f(pp[(size_t)(ic + 1) * 65536]);
            s2 += bf2f(pp[(size_t)(ic + 2) * 65536]);
            s3 += bf2f(pp[(size_t)(ic + 3) * 65536]);
        }
        ws_[hh][j] = (s0 + s1) + (s2 + s3);
    }
    __syncthreads();

    float a0 = 0.f, a1 = 0.f, a2 = 0.f, a3 = 0.f;
    const ushort* xcol = xh + ((size_t)(b * N_ + j0)) * F_ + tid;
    #pragma unroll 4
    for (int j = 0; j < 64; ++j) {
        const float xv = bf2f(xcol[(size_t)j * F_]);
        a0 = fmaf(ws_[0][j], xv, a0);
        a1 = fmaf(ws_[1][j], xv, a1);
        a2 = fmaf(ws_[2][j], xv, a2);
        a3 = fmaf(ws_[3][j], xv, a3);
    }
    float* yp = ypart + (size_t)(b * 16 + jc) * (H_ * F_) + tid;
    yp[0 * F_] = a0; yp[1 * F_] = a1; yp[2 * F_] = a2; yp[3 * F_] = a3;
}

// ---------------------------------------------------------------------------
// K3b: out[b, h*128+v] = sum_f (sum_jc ypart[b,jc,h,f]) * Wv[h,f,v]
// ---------------------------------------------------------------------------
__global__ __launch_bounds__(256) void pool_kernel(
    const float* __restrict__ ypart, const float* __restrict__ Wv,
    float* __restrict__ out)
{
    const int tid = threadIdx.x;
    const int bh  = blockIdx.x;
    const int b   = bh >> 2;
    const int h   = bh & 3;
    __shared__ float ys[256];
    float s = 0.f;
    #pragma unroll
    for (int jc = 0; jc < 16; ++jc)
        s += ypart[(size_t)(b * 16 + jc) * (H_ * F_) + h * F_ + tid];
    ys[tid] = s;
    __syncthreads();
    if (tid < 128) {
        float acc = 0.f;
        const float* wv = Wv + h * (F_ * 128) + tid;
        #pragma unroll 4
        for (int f = 0; f < F_; ++f) acc = fmaf(ys[f], wv[f * 128], acc);
        out[bh * 128 + tid] = acc;
    }
}

extern "C" void kernel_launch(void* const* d_in, const int* in_sizes, int n_in,
                              void* d_out, int out_size, void* d_ws, size_t ws_size,
                              hipStream_t stream) {
    const float* e    = (const float*)d_in[0];
    const float* x    = (const float*)d_in[1];
    const float* mask = (const float*)d_in[2];
    const float* eps  = (const float*)d_in[3];
    const float* Wq   = (const float*)d_in[4];
    const float* Wk   = (const float*)d_in[5];
    const float* Wv   = (const float*)d_in[6];
    const float* aq   = (const float*)d_in[7];
    const float* bq   = (const float*)d_in[8];
    const float* ak   = (const float*)d_in[9];
    const float* bk   = (const float*)d_in[10];

    float*  qbuf  = (float*)d_ws;              // [B,H,N]         65536 f32
    float*  kbuf  = qbuf + 65536;              // [B,H,N]         65536 f32
    float*  ypartb= kbuf + 65536;              // [B,16,H,F]     262144 f32
    ushort* pbuf  = (ushort*)(ypartb + 262144);// [64,B,H,N] bf16 4194304
    ushort* xh    = pbuf + 4194304;            // [B*N,F] bf16   4194304
    ushort* Wqt   = xh + 4194304;              // [H,Q,F] bf16    131072
    ushort* Wkt   = Wqt + 131072;              // [H,Q,F] bf16    131072
    float*  outf  = (float*)d_out;

    convert_all<<<3072, 256, 0, stream>>>((const float4*)x, (ushort4*)xh, Wq, Wk, Wqt, Wkt);
    qk_mfma<<<dim3(256, 4, 2), 256, 0, stream>>>(xh, Wqt, Wkt, aq, bq, ak, bk, qbuf, kbuf);
    attn_kernel<<<dim3(64, 16), 512, 0, stream>>>(e, qbuf, kbuf, mask, eps, pbuf);
    ypart_kernel<<<256, 256, 0, stream>>>(xh, pbuf, ypartb);
    pool_kernel<<<64, 256, 0, stream>>>(ypartb, Wv, outf);
}